// Round 4
// baseline (8987.533 us; speedup 1.0000x reference)
//
#include <hip/hip_runtime.h>
#include <hip/hip_bf16.h>

typedef __attribute__((ext_vector_type(8)))  short short8;
typedef __attribute__((ext_vector_type(16))) float f32x16;

#define TSTEPS 1024
#define BATCH  128
#define NIN    256
#define NHID   512
#define GM     4      // batch groups (columns)
#define GHB    16     // h-slice groups per column
#define MBLK   32     // batch rows per block
#define NHB    32     // h cols per block
#define LDSW   776    // in_lds row stride in bf16 elems (768 + 8 pad, 16B-aligned rows)

__device__ __forceinline__ unsigned short f2bf(float f) {
  unsigned int u = __builtin_bit_cast(unsigned int, f);
  u += 0x7fffu + ((u >> 16) & 1u);
  return (unsigned short)(u >> 16);
}

__device__ __forceinline__ unsigned long long pack4(float a, float b, float c, float d) {
  return (unsigned long long)f2bf(a)
       | ((unsigned long long)f2bf(b) << 16)
       | ((unsigned long long)f2bf(c) << 32)
       | ((unsigned long long)f2bf(d) << 48);
}

__device__ __forceinline__ float sigf(float x) {
  return 1.0f / (1.0f + __expf(-x));
}
__device__ __forceinline__ float tanh_fast(float x) {
  x = fminf(fmaxf(x, -15.0f), 15.0f);
  float e = __expf(2.0f * x);
  return (e - 1.0f) / (e + 1.0f);
}

// Zero h double-buffer slot 0 (128*512 bf16 = 16384 u64) and the 64 slice flags
// (4 groups x 16 slices, 32-u32 = 128B spacing -> 2048 u32).
__global__ void init_ws_kernel(unsigned long long* hbuf, unsigned int* flags) {
  int idx = blockIdx.x * blockDim.x + threadIdx.x;
  if (idx < 16384) hbuf[idx] = 0ull;
  if (idx < 2048) flags[idx] = 0u;
}

__global__ __launch_bounds__(256, 1) void lstm_persistent(
    const float* __restrict__ x,      // [1024][128][256]
    const float* __restrict__ Wih,    // [2048][256]
    const float* __restrict__ Whh,    // [2048][512]
    const float* __restrict__ bih,    // [2048]
    const float* __restrict__ bhh,    // [2048]
    float* __restrict__ out,          // [3*128*512] = h, h, c
    unsigned long long* __restrict__ hbuf,  // [2][128][512] bf16, u64 units
    unsigned int* __restrict__ flags)       // [4][16] u32, stride 32 (one line each)
{
  const int tid  = threadIdx.x;
  const int lane = tid & 63;
  const int wv   = tid >> 6;              // wave 0..3
  const int gm   = blockIdx.x & (GM - 1); // batch group
  const int gh   = blockIdx.x >> 2;       // h-slice group 0..15
  const int m0   = gm * MBLK;
  const int hc0  = gh * NHB;

  __shared__ short in_lds[MBLK][LDSW];    // [32][776] bf16: cols 0..255 = x, 256..767 = h
  __shared__ float z_lds[4][32][36];      // per-wave 32x32 z tile, padded stride 36

  // ---------------- W fragments -> registers (B operand, stays for all 1024 steps) ----
  // wave tile col n (0..31): gate = n>>3, local h-col = wv*8 + (n&7)
  const int ncol = lane & 31;
  const int kg   = (lane >> 5) * 8;       // k sub-offset within a K=16 fragment
  const int gate = ncol >> 3;
  const int wrow = gate * NHID + hc0 + wv * 8 + (ncol & 7);   // global gate row 0..2047

  short8 bfrag[48];
#pragma unroll
  for (int kb = 0; kb < 48; ++kb) {
    const float* src = (kb < 16)
        ? (Wih + (size_t)wrow * NIN  + (kb * 16 + kg))
        : (Whh + (size_t)wrow * NHID + (kb * 16 + kg - NIN));
    float4 f0 = *(const float4*)src;
    float4 f1 = *(const float4*)(src + 4);
    short8 b;
    b[0] = (short)f2bf(f0.x); b[1] = (short)f2bf(f0.y);
    b[2] = (short)f2bf(f0.z); b[3] = (short)f2bf(f0.w);
    b[4] = (short)f2bf(f1.x); b[5] = (short)f2bf(f1.y);
    b[6] = (short)f2bf(f1.z); b[7] = (short)f2bf(f1.w);
    bfrag[kb] = b;
  }

  // bias folded into the accumulator init: this lane's z-col bias
  const float bias_c = bih[wrow] + bhh[wrow];

  // ---------------- gate-phase constants; cell state lives in registers ----------------
  const int grow = tid >> 3;        // c-tile row 0..31
  const int c4   = (tid & 7) * 4;   // c-tile col base 0,4,...,28
  float creg[4] = {0.0f, 0.0f, 0.0f, 0.0f};

  const short* abase = &in_lds[lane & 31][kg];
  unsigned int* fgrp   = flags + gm * (GHB * 32);
  unsigned int* myflag = fgrp + gh * 32;

  for (int t = 0; t < TSTEPS; ++t) {
    // ---------------- stage x_t (fp32 -> bf16), independent of h: overlaps the wait ----
    {
      const float* xt = x + ((size_t)t * BATCH + m0) * NIN;
#pragma unroll
      for (int i = 0; i < 8; ++i) {
        int u  = tid + 256 * i;        // 0..2047 units of 4 floats
        int r  = u >> 6;
        int cu = (u & 63) * 4;
        float4 f = *(const float4*)(xt + (size_t)r * NIN + cu);
        *(unsigned long long*)&in_lds[r][cu] = pack4(f.x, f.y, f.z, f.w);
      }
    }

    // ---------------- wait for h_t: wave 0 polls all 16 slice flags in parallel -------
    if (wv == 0 && t > 0) {
      const unsigned int* fp = fgrp + (lane & (GHB - 1)) * 32;
      unsigned int v = __hip_atomic_load(fp, __ATOMIC_RELAXED, __HIP_MEMORY_SCOPE_AGENT);
      while (!__all((int)(v >= (unsigned int)t))) {
        __builtin_amdgcn_s_sleep(1);
        v = __hip_atomic_load(fp, __ATOMIC_RELAXED, __HIP_MEMORY_SCOPE_AGENT);
      }
    }
    __syncthreads();

    // ---------------- stage h_t (coherent u64 loads) ----------------
    {
      const unsigned long long* hsrc = hbuf + (size_t)(t & 1) * 16384 + (size_t)m0 * 128;
#pragma unroll
      for (int i = 0; i < 16; ++i) {
        int u  = tid + 256 * i;        // 0..4095 units of 4 bf16
        int r  = u >> 7;
        int cu = (u & 127) * 4;
        unsigned long long v =
            __hip_atomic_load(hsrc + u, __ATOMIC_RELAXED, __HIP_MEMORY_SCOPE_AGENT);
        *(unsigned long long*)&in_lds[r][NIN + cu] = v;
      }
    }
    __syncthreads();

    // ---------------- MFMA: z(32x32) = in(32x768) * W^T, 4 acc chains ----------------
    f32x16 a0 = (f32x16)bias_c;   // bias pre-folded into chain 0
    f32x16 a1 = (f32x16)0.0f, a2 = (f32x16)0.0f, a3 = (f32x16)0.0f;
#pragma unroll
    for (int kb = 0; kb < 48; kb += 4) {
      short8 v0 = *(const short8*)(abase + (kb + 0) * 16);
      a0 = __builtin_amdgcn_mfma_f32_32x32x16_bf16(v0, bfrag[kb + 0], a0, 0, 0, 0);
      short8 v1 = *(const short8*)(abase + (kb + 1) * 16);
      a1 = __builtin_amdgcn_mfma_f32_32x32x16_bf16(v1, bfrag[kb + 1], a1, 0, 0, 0);
      short8 v2 = *(const short8*)(abase + (kb + 2) * 16);
      a2 = __builtin_amdgcn_mfma_f32_32x32x16_bf16(v2, bfrag[kb + 2], a2, 0, 0, 0);
      short8 v3 = *(const short8*)(abase + (kb + 3) * 16);
      a3 = __builtin_amdgcn_mfma_f32_32x32x16_bf16(v3, bfrag[kb + 3], a3, 0, 0, 0);
    }
    {
      f32x16 acc = (a0 + a1) + (a2 + a3);
      // C/D layout (m74): col = lane&31, row = (reg&3) + 8*(reg>>2) + 4*(lane>>5)
#pragma unroll
      for (int r = 0; r < 16; ++r) {
        int zr = (r & 3) + 8 * (r >> 2) + 4 * (lane >> 5);
        z_lds[wv][zr][ncol] = acc[r];
      }
    }
    __syncthreads();

    // ---------------- gates + cell update (bias already in z) ----------------
    {
      const int wz = c4 >> 3;      // which wave's z tile holds these cols
      const int cc = c4 & 7;
      float hnv[4];
#pragma unroll
      for (int u = 0; u < 4; ++u) {
        float zi = z_lds[wz][grow][ 0 + cc + u];
        float zf = z_lds[wz][grow][ 8 + cc + u];
        float zg = z_lds[wz][grow][16 + cc + u];
        float zo = z_lds[wz][grow][24 + cc + u];
        float iv = sigf(zi);
        float fv = sigf(zf);
        float gv = tanh_fast(zg);
        float ov = sigf(zo);
        float cn = fv * creg[u] + iv * gv;
        creg[u] = cn;
        hnv[u] = ov * tanh_fast(cn);
      }
      if (t == TSTEPS - 1) {
        size_t o = (size_t)(m0 + grow) * NHID + hc0 + c4;
#pragma unroll
        for (int u = 0; u < 4; ++u) {
          out[o + u]          = hnv[u];   // output
          out[65536 + o + u]  = hnv[u];   // h_n
          out[131072 + o + u] = creg[u];  // c_n
        }
      } else {
        unsigned long long hp = pack4(hnv[0], hnv[1], hnv[2], hnv[3]);
        size_t hoff = (size_t)((t + 1) & 1) * 16384
                    + (size_t)(m0 + grow) * 128 + (hc0 + c4) / 4;
        __hip_atomic_store(hbuf + hoff, hp, __ATOMIC_RELAXED, __HIP_MEMORY_SCOPE_AGENT);
      }
    }

    // ---------------- publish: drain h stores, then one flag store (no RMW) ----------
    if (t < TSTEPS - 1) {
      __syncthreads();   // each wave drains its vmcnt before the barrier -> h visible
      if (tid == 0) {
        __hip_atomic_store(myflag, (unsigned int)(t + 1),
                           __ATOMIC_RELAXED, __HIP_MEMORY_SCOPE_AGENT);
      }
    }
  }
}

extern "C" void kernel_launch(void* const* d_in, const int* in_sizes, int n_in,
                              void* d_out, int out_size, void* d_ws, size_t ws_size,
                              hipStream_t stream) {
  const float* x   = (const float*)d_in[0];
  const float* Wih = (const float*)d_in[1];
  const float* Whh = (const float*)d_in[2];
  const float* bih = (const float*)d_in[3];
  const float* bhh = (const float*)d_in[4];
  float* out = (float*)d_out;

  unsigned long long* hbuf = (unsigned long long*)d_ws;                 // 262144 B
  unsigned int* flags = (unsigned int*)((char*)d_ws + 262144);          // 2048 u32

  hipLaunchKernelGGL(init_ws_kernel, dim3(64), dim3(256), 0, stream, hbuf, flags);
  hipLaunchKernelGGL(lstm_persistent, dim3(64), dim3(256), 0, stream,
                     x, Wih, Whh, bih, bhh, out, hbuf, flags);
}

// Round 5
// 5710.258 us; speedup vs baseline: 1.5739x; 1.5739x over previous
//
#include <hip/hip_runtime.h>
#include <hip/hip_bf16.h>

typedef __attribute__((ext_vector_type(8)))  short short8;
typedef __attribute__((ext_vector_type(16))) float f32x16;
typedef __attribute__((ext_vector_type(4)))  unsigned int uint4v;

#define TSTEPS 1024
#define BATCH  128
#define NIN    256
#define NHID   512
#define GM     4      // batch groups (columns)
#define GHB    16     // h-slice groups per column
#define MBLK   32     // batch rows per block
#define NHB    32     // h cols per block
#define LDSW   776    // in_lds row stride in bf16 elems (768 + 8 pad; 1552B = 97*16, 16B-aligned rows)

__device__ __forceinline__ unsigned short f2bf(float f) {
  unsigned int u = __builtin_bit_cast(unsigned int, f);
  u += 0x7fffu + ((u >> 16) & 1u);
  return (unsigned short)(u >> 16);
}

__device__ __forceinline__ unsigned long long pack4(float a, float b, float c, float d) {
  return (unsigned long long)f2bf(a)
       | ((unsigned long long)f2bf(b) << 16)
       | ((unsigned long long)f2bf(c) << 32)
       | ((unsigned long long)f2bf(d) << 48);
}

__device__ __forceinline__ float sigf(float x) {
  return 1.0f / (1.0f + __expf(-x));
}
__device__ __forceinline__ float tanh_fast(float x) {
  x = fminf(fmaxf(x, -15.0f), 15.0f);
  float e = __expf(2.0f * x);
  return (e - 1.0f) / (e + 1.0f);
}

// Zero h double-buffer slot 0 (128*512 bf16 = 16384 u64) and the 64 slice flags
// (4 groups x 16 slices, 32-u32 = 128B spacing -> 2048 u32).
__global__ void init_ws_kernel(unsigned long long* hbuf, unsigned int* flags) {
  int idx = blockIdx.x * blockDim.x + threadIdx.x;
  if (idx < 16384) hbuf[idx] = 0ull;
  if (idx < 2048) flags[idx] = 0u;
}

__global__ __launch_bounds__(256, 1) void lstm_persistent(
    const float* __restrict__ x,      // [1024][128][256]
    const float* __restrict__ Wih,    // [2048][256]
    const float* __restrict__ Whh,    // [2048][512]
    const float* __restrict__ bih,    // [2048]
    const float* __restrict__ bhh,    // [2048]
    float* __restrict__ out,          // [3*128*512] = h, h, c
    unsigned long long* __restrict__ hbuf,  // [2][128][512] bf16, u64 units
    unsigned int* __restrict__ flags)       // [4][16] u32, stride 32 (one line each)
{
  const int tid  = threadIdx.x;
  const int lane = tid & 63;
  const int wv   = tid >> 6;              // wave 0..3
  const int gm   = blockIdx.x & (GM - 1); // batch group
  const int gh   = blockIdx.x >> 2;       // h-slice group 0..15
  const int m0   = gm * MBLK;
  const int hc0  = gh * NHB;

  __shared__ short in_lds[MBLK][LDSW];    // [32][776] bf16: cols 0..255 = x, 256..767 = h
  __shared__ float z_lds[4][32][36];      // per-wave 32x32 z tile, padded stride 36

  // ---------------- W fragments -> registers (B operand, stays for all 1024 steps) ----
  // wave tile col n (0..31): gate = n>>3, local h-col = wv*8 + (n&7)
  const int ncol = lane & 31;
  const int kg   = (lane >> 5) * 8;       // k sub-offset within a K=16 fragment
  const int gate = ncol >> 3;
  const int wrow = gate * NHID + hc0 + wv * 8 + (ncol & 7);   // global gate row 0..2047

  short8 bfrag[48];
#pragma unroll
  for (int kb = 0; kb < 48; ++kb) {
    const float* src = (kb < 16)
        ? (Wih + (size_t)wrow * NIN  + (kb * 16 + kg))
        : (Whh + (size_t)wrow * NHID + (kb * 16 + kg - NIN));
    float4 f0 = *(const float4*)src;
    float4 f1 = *(const float4*)(src + 4);
    short8 b;
    b[0] = (short)f2bf(f0.x); b[1] = (short)f2bf(f0.y);
    b[2] = (short)f2bf(f0.z); b[3] = (short)f2bf(f0.w);
    b[4] = (short)f2bf(f1.x); b[5] = (short)f2bf(f1.y);
    b[6] = (short)f2bf(f1.z); b[7] = (short)f2bf(f1.w);
    bfrag[kb] = b;
  }

  // bias folded into the accumulator init: this lane's z-col bias
  const float bias_c = bih[wrow] + bhh[wrow];

  // ---------------- gate-phase constants; cell state lives in registers ----------------
  const int grow = tid >> 3;        // c-tile row 0..31
  const int c4   = (tid & 7) * 4;   // c-tile col base 0,4,...,28
  float creg[4] = {0.0f, 0.0f, 0.0f, 0.0f};

  const short* abase = &in_lds[lane & 31][kg];
  unsigned int* fgrp   = flags + gm * (GHB * 32);
  unsigned int* myflag = fgrp + gh * 32;

  for (int t = 0; t < TSTEPS; ++t) {
    // ---------------- stage x_t (fp32 -> bf16), independent of h: overlaps the wait ----
    {
      const float* xt = x + ((size_t)t * BATCH + m0) * NIN;
#pragma unroll
      for (int i = 0; i < 8; ++i) {
        int u  = tid + 256 * i;        // 0..2047 units of 4 floats
        int r  = u >> 6;
        int cu = (u & 63) * 4;
        float4 f = *(const float4*)(xt + (size_t)r * NIN + cu);
        *(unsigned long long*)&in_lds[r][cu] = pack4(f.x, f.y, f.z, f.w);
      }
    }

    // ---------------- wait for h_t: wave 0 polls all 16 slice flags in parallel -------
    if (wv == 0 && t > 0) {
      const unsigned int* fp = fgrp + (lane & (GHB - 1)) * 32;
      unsigned int v = __hip_atomic_load(fp, __ATOMIC_RELAXED, __HIP_MEMORY_SCOPE_AGENT);
      while (!__all((int)(v >= (unsigned int)t))) {
        __builtin_amdgcn_s_sleep(1);
        v = __hip_atomic_load(fp, __ATOMIC_RELAXED, __HIP_MEMORY_SCOPE_AGENT);
      }
    }
    __syncthreads();

    // ---------------- stage h_t: 8 pipelined coherent 16B loads, ONE waitcnt ----------
    {
      const char* hbase = (const char*)(hbuf + (size_t)(t & 1) * 16384 + (size_t)m0 * 128);
      uint4v hv0, hv1, hv2, hv3, hv4, hv5, hv6, hv7;
      const char* p = hbase + tid * 16;
      asm volatile("global_load_dwordx4 %0, %1, off sc0 sc1" : "=v"(hv0) : "v"(p + 0 * 4096));
      asm volatile("global_load_dwordx4 %0, %1, off sc0 sc1" : "=v"(hv1) : "v"(p + 1 * 4096));
      asm volatile("global_load_dwordx4 %0, %1, off sc0 sc1" : "=v"(hv2) : "v"(p + 2 * 4096));
      asm volatile("global_load_dwordx4 %0, %1, off sc0 sc1" : "=v"(hv3) : "v"(p + 3 * 4096));
      asm volatile("global_load_dwordx4 %0, %1, off sc0 sc1" : "=v"(hv4) : "v"(p + 4 * 4096));
      asm volatile("global_load_dwordx4 %0, %1, off sc0 sc1" : "=v"(hv5) : "v"(p + 5 * 4096));
      asm volatile("global_load_dwordx4 %0, %1, off sc0 sc1" : "=v"(hv6) : "v"(p + 6 * 4096));
      asm volatile("global_load_dwordx4 %0, %1, off sc0 sc1" : "=v"(hv7) : "v"(p + 7 * 4096));
      asm volatile("s_waitcnt vmcnt(0)" ::: "memory");
      __builtin_amdgcn_sched_barrier(0);
      // u = tid + 256*i indexes 16B chunks: row = u>>6 (1024B/row), col8 = (u&63)*8
#pragma unroll
      for (int i = 0; i < 8; ++i) {
        int u  = tid + 256 * i;
        int r  = u >> 6;
        int cu = (u & 63) * 8;
        uint4v v = (i == 0) ? hv0 : (i == 1) ? hv1 : (i == 2) ? hv2 : (i == 3) ? hv3
                 : (i == 4) ? hv4 : (i == 5) ? hv5 : (i == 6) ? hv6 : hv7;
        *(uint4v*)&in_lds[r][NIN + cu] = v;
      }
    }
    __syncthreads();

    // ---------------- MFMA: z(32x32) = in(32x768) * W^T, 4 acc chains ----------------
    f32x16 a0 = (f32x16)bias_c;   // bias pre-folded into chain 0
    f32x16 a1 = (f32x16)0.0f, a2 = (f32x16)0.0f, a3 = (f32x16)0.0f;
#pragma unroll
    for (int kb = 0; kb < 48; kb += 4) {
      short8 v0 = *(const short8*)(abase + (kb + 0) * 16);
      a0 = __builtin_amdgcn_mfma_f32_32x32x16_bf16(v0, bfrag[kb + 0], a0, 0, 0, 0);
      short8 v1 = *(const short8*)(abase + (kb + 1) * 16);
      a1 = __builtin_amdgcn_mfma_f32_32x32x16_bf16(v1, bfrag[kb + 1], a1, 0, 0, 0);
      short8 v2 = *(const short8*)(abase + (kb + 2) * 16);
      a2 = __builtin_amdgcn_mfma_f32_32x32x16_bf16(v2, bfrag[kb + 2], a2, 0, 0, 0);
      short8 v3 = *(const short8*)(abase + (kb + 3) * 16);
      a3 = __builtin_amdgcn_mfma_f32_32x32x16_bf16(v3, bfrag[kb + 3], a3, 0, 0, 0);
    }
    {
      f32x16 acc = (a0 + a1) + (a2 + a3);
      // C/D layout (m74): col = lane&31, row = (reg&3) + 8*(reg>>2) + 4*(lane>>5)
#pragma unroll
      for (int r = 0; r < 16; ++r) {
        int zr = (r & 3) + 8 * (r >> 2) + 4 * (lane >> 5);
        z_lds[wv][zr][ncol] = acc[r];
      }
    }
    __syncthreads();

    // ---------------- gates + cell update (bias already in z) ----------------
    {
      const int wz = c4 >> 3;      // which wave's z tile holds these cols
      const int cc = c4 & 7;
      float hnv[4];
#pragma unroll
      for (int u = 0; u < 4; ++u) {
        float zi = z_lds[wz][grow][ 0 + cc + u];
        float zf = z_lds[wz][grow][ 8 + cc + u];
        float zg = z_lds[wz][grow][16 + cc + u];
        float zo = z_lds[wz][grow][24 + cc + u];
        float iv = sigf(zi);
        float fv = sigf(zf);
        float gv = tanh_fast(zg);
        float ov = sigf(zo);
        float cn = fv * creg[u] + iv * gv;
        creg[u] = cn;
        hnv[u] = ov * tanh_fast(cn);
      }
      if (t == TSTEPS - 1) {
        size_t o = (size_t)(m0 + grow) * NHID + hc0 + c4;
#pragma unroll
        for (int u = 0; u < 4; ++u) {
          out[o + u]          = hnv[u];   // output
          out[65536 + o + u]  = hnv[u];   // h_n
          out[131072 + o + u] = creg[u];  // c_n
        }
      } else {
        unsigned long long hp = pack4(hnv[0], hnv[1], hnv[2], hnv[3]);
        size_t hoff = (size_t)((t + 1) & 1) * 16384
                    + (size_t)(m0 + grow) * 128 + (hc0 + c4) / 4;
        __hip_atomic_store(hbuf + hoff, hp, __ATOMIC_RELAXED, __HIP_MEMORY_SCOPE_AGENT);
      }
    }

    // ---------------- publish: drain h stores, then one flag store (no RMW) ----------
    if (t < TSTEPS - 1) {
      __syncthreads();   // each wave drains its vmcnt before the barrier -> h visible
      if (tid == 0) {
        __hip_atomic_store(myflag, (unsigned int)(t + 1),
                           __ATOMIC_RELAXED, __HIP_MEMORY_SCOPE_AGENT);
      }
    }
  }
}

extern "C" void kernel_launch(void* const* d_in, const int* in_sizes, int n_in,
                              void* d_out, int out_size, void* d_ws, size_t ws_size,
                              hipStream_t stream) {
  const float* x   = (const float*)d_in[0];
  const float* Wih = (const float*)d_in[1];
  const float* Whh = (const float*)d_in[2];
  const float* bih = (const float*)d_in[3];
  const float* bhh = (const float*)d_in[4];
  float* out = (float*)d_out;

  unsigned long long* hbuf = (unsigned long long*)d_ws;                 // 262144 B
  unsigned int* flags = (unsigned int*)((char*)d_ws + 262144);          // 2048 u32

  hipLaunchKernelGGL(init_ws_kernel, dim3(64), dim3(256), 0, stream, hbuf, flags);
  hipLaunchKernelGGL(lstm_persistent, dim3(64), dim3(256), 0, stream,
                     x, Wih, Whh, bih, bhh, out, hbuf, flags);
}

// Round 6
// 3751.748 us; speedup vs baseline: 2.3956x; 1.5220x over previous
//
#include <hip/hip_runtime.h>
#include <hip/hip_bf16.h>

typedef __attribute__((ext_vector_type(8)))  short short8;
typedef __attribute__((ext_vector_type(16))) float f32x16;
typedef __attribute__((ext_vector_type(4)))  unsigned int uint4v;

#define TSTEPS 1024
#define BATCH  128
#define NIN    256
#define NHID   512
#define GM     4      // batch groups (columns)
#define GHB    16     // h-slice groups per column
#define MBLK   32     // batch rows per block
#define NHB    32     // h cols per block
#define LDSW   776    // in_lds row stride in bf16 elems (768 + 8 pad; 1552B rows, 16B-aligned)

__device__ __forceinline__ unsigned short f2bf(float f) {
  unsigned int u = __builtin_bit_cast(unsigned int, f);
  u += 0x7fffu + ((u >> 16) & 1u);
  return (unsigned short)(u >> 16);
}

__device__ __forceinline__ unsigned long long pack4(float a, float b, float c, float d) {
  return (unsigned long long)f2bf(a)
       | ((unsigned long long)f2bf(b) << 16)
       | ((unsigned long long)f2bf(c) << 32)
       | ((unsigned long long)f2bf(d) << 48);
}

__device__ __forceinline__ float sigf(float x) {
  return 1.0f / (1.0f + __expf(-x));
}
__device__ __forceinline__ float tanh_fast(float x) {
  x = fminf(fmaxf(x, -15.0f), 15.0f);
  float e = __expf(2.0f * x);
  return (e - 1.0f) / (e + 1.0f);
}

// Zero h double-buffer slot 0 (128*512 bf16 = 16384 u64) and the 64 slice flags
// (4 groups x 16 slices, 32-u32 = 128B spacing -> 2048 u32).
__global__ void init_ws_kernel(unsigned long long* hbuf, unsigned int* flags) {
  int idx = blockIdx.x * blockDim.x + threadIdx.x;
  if (idx < 16384) hbuf[idx] = 0ull;
  if (idx < 2048) flags[idx] = 0u;
}

__global__ __launch_bounds__(256, 1) void lstm_persistent(
    const float* __restrict__ x,      // [1024][128][256]
    const float* __restrict__ Wih,    // [2048][256]
    const float* __restrict__ Whh,    // [2048][512]
    const float* __restrict__ bih,    // [2048]
    const float* __restrict__ bhh,    // [2048]
    float* __restrict__ out,          // [3*128*512] = h, h, c
    unsigned long long* __restrict__ hbuf,  // [2][128][512] bf16, u64 units
    unsigned int* __restrict__ flags)       // [4][16] u32, stride 32 (one line each)
{
  const int tid  = threadIdx.x;
  const int lane = tid & 63;
  const int wv   = tid >> 6;              // wave 0..3
  const int gm   = blockIdx.x & (GM - 1); // batch group
  const int gh   = blockIdx.x >> 2;       // h-slice group 0..15
  const int m0   = gm * MBLK;
  const int hc0  = gh * NHB;

  __shared__ short in_lds[MBLK][LDSW];    // [32][776] bf16: cols 0..255 = x, 256..767 = h
  __shared__ float z_lds[4][32][36];      // per-wave 32x32 z tile, padded stride 36

  // ---------------- W fragments -> registers (B operand, stays for all 1024 steps) ----
  // wave tile col n (0..31): gate = n>>3, local h-col = wv*8 + (n&7)
  const int ncol = lane & 31;
  const int kg   = (lane >> 5) * 8;       // k sub-offset within a K=16 fragment
  const int gate = ncol >> 3;
  const int wrow = gate * NHID + hc0 + wv * 8 + (ncol & 7);   // global gate row 0..2047

  short8 bfrag[48];
#pragma unroll
  for (int kb = 0; kb < 48; ++kb) {
    const float* src = (kb < 16)
        ? (Wih + (size_t)wrow * NIN  + (kb * 16 + kg))
        : (Whh + (size_t)wrow * NHID + (kb * 16 + kg - NIN));
    float4 f0 = *(const float4*)src;
    float4 f1 = *(const float4*)(src + 4);
    short8 b;
    b[0] = (short)f2bf(f0.x); b[1] = (short)f2bf(f0.y);
    b[2] = (short)f2bf(f0.z); b[3] = (short)f2bf(f0.w);
    b[4] = (short)f2bf(f1.x); b[5] = (short)f2bf(f1.y);
    b[6] = (short)f2bf(f1.z); b[7] = (short)f2bf(f1.w);
    bfrag[kb] = b;
  }

  // bias folded into the accumulator init: this lane's z-col bias
  const float bias_c = bih[wrow] + bhh[wrow];

  // ---------------- gate-phase constants; cell state lives in registers ----------------
  const int grow = tid >> 3;        // c-tile row 0..31
  const int c4   = (tid & 7) * 4;   // c-tile col base 0,4,...,28
  float creg[4] = {0.0f, 0.0f, 0.0f, 0.0f};

  const short* abase = &in_lds[lane & 31][kg];
  unsigned int* fgrp   = flags + gm * (GHB * 32);
  unsigned int* myflag = fgrp + gh * 32;

  // x staging index decomposition: u = tid + 256*i -> row u>>6, col4 (u&63)*4
#define XLOAD(i, v) { int u = tid + 256 * (i); \
    v = *(const float4*)(xt + (size_t)(u >> 6) * NIN + (u & 63) * 4); }
#define XPACK(i, v) { int u = tid + 256 * (i); \
    *(unsigned long long*)&in_lds[u >> 6][(u & 63) * 4] = pack4(v.x, v.y, v.z, v.w); }

  f32x16 a0, a1, a2, a3;
  float4 xv0, xv1, xv2, xv3, xv4, xv5, xv6, xv7;

  // ---------------- prologue: stage x_0, compute zx_0 ----------------
  {
    const float* xt = x + (size_t)m0 * NIN;
    XLOAD(0, xv0) XLOAD(1, xv1) XLOAD(2, xv2) XLOAD(3, xv3)
    XLOAD(4, xv4) XLOAD(5, xv5) XLOAD(6, xv6) XLOAD(7, xv7)
    XPACK(0, xv0) XPACK(1, xv1) XPACK(2, xv2) XPACK(3, xv3)
    XPACK(4, xv4) XPACK(5, xv5) XPACK(6, xv6) XPACK(7, xv7)
  }
  __syncthreads();
  a0 = (f32x16)bias_c;
  a1 = (f32x16)0.0f; a2 = (f32x16)0.0f; a3 = (f32x16)0.0f;
#pragma unroll
  for (int kb = 0; kb < 16; kb += 4) {
    short8 v0 = *(const short8*)(abase + (kb + 0) * 16);
    a0 = __builtin_amdgcn_mfma_f32_32x32x16_bf16(v0, bfrag[kb + 0], a0, 0, 0, 0);
    short8 v1 = *(const short8*)(abase + (kb + 1) * 16);
    a1 = __builtin_amdgcn_mfma_f32_32x32x16_bf16(v1, bfrag[kb + 1], a1, 0, 0, 0);
    short8 v2 = *(const short8*)(abase + (kb + 2) * 16);
    a2 = __builtin_amdgcn_mfma_f32_32x32x16_bf16(v2, bfrag[kb + 2], a2, 0, 0, 0);
    short8 v3 = *(const short8*)(abase + (kb + 3) * 16);
    a3 = __builtin_amdgcn_mfma_f32_32x32x16_bf16(v3, bfrag[kb + 3], a3, 0, 0, 0);
  }

  for (int t = 0; t < TSTEPS; ++t) {
    // -------- wait for h_{t-1}: ALL waves poll the 16 slice flags in parallel --------
    {
      const unsigned int* fp = fgrp + (lane & (GHB - 1)) * 32;
      unsigned int v = __hip_atomic_load(fp, __ATOMIC_RELAXED, __HIP_MEMORY_SCOPE_AGENT);
      while (!__all((int)(v >= (unsigned int)t))) {
        __builtin_amdgcn_s_sleep(1);
        v = __hip_atomic_load(fp, __ATOMIC_RELAXED, __HIP_MEMORY_SCOPE_AGENT);
      }
    }

    // -------- stage h_{t-1}: 8 pipelined coherent 16B loads, ONE waitcnt ------------
    {
      const char* hbase = (const char*)(hbuf + (size_t)(t & 1) * 16384 + (size_t)m0 * 128);
      uint4v hv0, hv1, hv2, hv3, hv4, hv5, hv6, hv7;
      const char* p = hbase + tid * 16;
      asm volatile("global_load_dwordx4 %0, %1, off sc0 sc1" : "=v"(hv0) : "v"(p + 0 * 4096));
      asm volatile("global_load_dwordx4 %0, %1, off sc0 sc1" : "=v"(hv1) : "v"(p + 1 * 4096));
      asm volatile("global_load_dwordx4 %0, %1, off sc0 sc1" : "=v"(hv2) : "v"(p + 2 * 4096));
      asm volatile("global_load_dwordx4 %0, %1, off sc0 sc1" : "=v"(hv3) : "v"(p + 3 * 4096));
      asm volatile("global_load_dwordx4 %0, %1, off sc0 sc1" : "=v"(hv4) : "v"(p + 4 * 4096));
      asm volatile("global_load_dwordx4 %0, %1, off sc0 sc1" : "=v"(hv5) : "v"(p + 5 * 4096));
      asm volatile("global_load_dwordx4 %0, %1, off sc0 sc1" : "=v"(hv6) : "v"(p + 6 * 4096));
      asm volatile("global_load_dwordx4 %0, %1, off sc0 sc1" : "=v"(hv7) : "v"(p + 7 * 4096));
      asm volatile("s_waitcnt vmcnt(0)" ::: "memory");
      __builtin_amdgcn_sched_barrier(0);
      // u = tid + 256*i indexes 16B chunks: row = u>>6 (1024B/row), col8 = (u&63)*8
#pragma unroll
      for (int i = 0; i < 8; ++i) {
        int u  = tid + 256 * i;
        int r  = u >> 6;
        int cu = (u & 63) * 8;
        uint4v v = (i == 0) ? hv0 : (i == 1) ? hv1 : (i == 2) ? hv2 : (i == 3) ? hv3
                 : (i == 4) ? hv4 : (i == 5) ? hv5 : (i == 6) ? hv6 : hv7;
        *(uint4v*)&in_lds[r][NIN + cu] = v;
      }
    }
    __syncthreads();                                    // (a) h tile visible

    // -------- 32 h-part MFMAs accumulate onto zx_t (kb 16..47) ----------------------
#pragma unroll
    for (int kb = 16; kb < 48; kb += 4) {
      short8 v0 = *(const short8*)(abase + (kb + 0) * 16);
      a0 = __builtin_amdgcn_mfma_f32_32x32x16_bf16(v0, bfrag[kb + 0], a0, 0, 0, 0);
      short8 v1 = *(const short8*)(abase + (kb + 1) * 16);
      a1 = __builtin_amdgcn_mfma_f32_32x32x16_bf16(v1, bfrag[kb + 1], a1, 0, 0, 0);
      short8 v2 = *(const short8*)(abase + (kb + 2) * 16);
      a2 = __builtin_amdgcn_mfma_f32_32x32x16_bf16(v2, bfrag[kb + 2], a2, 0, 0, 0);
      short8 v3 = *(const short8*)(abase + (kb + 3) * 16);
      a3 = __builtin_amdgcn_mfma_f32_32x32x16_bf16(v3, bfrag[kb + 3], a3, 0, 0, 0);
    }
    {
      f32x16 acc = (a0 + a1) + (a2 + a3);
      // C/D layout (m74): col = lane&31, row = (reg&3) + 8*(reg>>2) + 4*(lane>>5)
#pragma unroll
      for (int r = 0; r < 16; ++r) {
        int zr = (r & 3) + 8 * (r >> 2) + 4 * (lane >> 5);
        z_lds[wv][zr][ncol] = acc[r];
      }
    }
    __syncthreads();                                    // (b) z tile visible

    // -------- issue x_{t+1} loads early: HBM latency hides under the gate phase -----
    if (t < TSTEPS - 1) {
      const float* xt = x + ((size_t)(t + 1) * BATCH + m0) * NIN;
      XLOAD(0, xv0) XLOAD(1, xv1) XLOAD(2, xv2) XLOAD(3, xv3)
      XLOAD(4, xv4) XLOAD(5, xv5) XLOAD(6, xv6) XLOAD(7, xv7)
    }

    // -------- gates + cell update (bias already in z) --------------------------------
    {
      const int wz = c4 >> 3;      // which wave's z tile holds these cols
      const int cc = c4 & 7;
      float hnv[4];
#pragma unroll
      for (int u = 0; u < 4; ++u) {
        float zi = z_lds[wz][grow][ 0 + cc + u];
        float zf = z_lds[wz][grow][ 8 + cc + u];
        float zg = z_lds[wz][grow][16 + cc + u];
        float zo = z_lds[wz][grow][24 + cc + u];
        float iv = sigf(zi);
        float fv = sigf(zf);
        float gv = tanh_fast(zg);
        float ov = sigf(zo);
        float cn = fv * creg[u] + iv * gv;
        creg[u] = cn;
        hnv[u] = ov * tanh_fast(cn);
      }
      if (t == TSTEPS - 1) {
        size_t o = (size_t)(m0 + grow) * NHID + hc0 + c4;
#pragma unroll
        for (int u = 0; u < 4; ++u) {
          out[o + u]          = hnv[u];   // output
          out[65536 + o + u]  = hnv[u];   // h_n
          out[131072 + o + u] = creg[u];  // c_n
        }
      } else {
        unsigned long long hp = pack4(hnv[0], hnv[1], hnv[2], hnv[3]);
        size_t hoff = (size_t)((t + 1) & 1) * 16384
                    + (size_t)(m0 + grow) * 128 + (hc0 + c4) / 4;
        __hip_atomic_store(hbuf + hoff, hp, __ATOMIC_RELAXED, __HIP_MEMORY_SCOPE_AGENT);
      }
    }

    __syncthreads();   // (c) drains h stores (and x loads, overlapped) -> h visible

    if (t < TSTEPS - 1) {
      // -------- publish flag (no RMW), then stage x_{t+1} and compute zx_{t+1} ------
      if (tid == 0) {
        __hip_atomic_store(myflag, (unsigned int)(t + 1),
                           __ATOMIC_RELAXED, __HIP_MEMORY_SCOPE_AGENT);
      }
      XPACK(0, xv0) XPACK(1, xv1) XPACK(2, xv2) XPACK(3, xv3)
      XPACK(4, xv4) XPACK(5, xv5) XPACK(6, xv6) XPACK(7, xv7)
      __syncthreads();                                  // (d) x tile visible
      a0 = (f32x16)bias_c;
      a1 = (f32x16)0.0f; a2 = (f32x16)0.0f; a3 = (f32x16)0.0f;
#pragma unroll
      for (int kb = 0; kb < 16; kb += 4) {
        short8 v0 = *(const short8*)(abase + (kb + 0) * 16);
        a0 = __builtin_amdgcn_mfma_f32_32x32x16_bf16(v0, bfrag[kb + 0], a0, 0, 0, 0);
        short8 v1 = *(const short8*)(abase + (kb + 1) * 16);
        a1 = __builtin_amdgcn_mfma_f32_32x32x16_bf16(v1, bfrag[kb + 1], a1, 0, 0, 0);
        short8 v2 = *(const short8*)(abase + (kb + 2) * 16);
        a2 = __builtin_amdgcn_mfma_f32_32x32x16_bf16(v2, bfrag[kb + 2], a2, 0, 0, 0);
        short8 v3 = *(const short8*)(abase + (kb + 3) * 16);
        a3 = __builtin_amdgcn_mfma_f32_32x32x16_bf16(v3, bfrag[kb + 3], a3, 0, 0, 0);
      }
    }
  }
#undef XLOAD
#undef XPACK
}

extern "C" void kernel_launch(void* const* d_in, const int* in_sizes, int n_in,
                              void* d_out, int out_size, void* d_ws, size_t ws_size,
                              hipStream_t stream) {
  const float* x   = (const float*)d_in[0];
  const float* Wih = (const float*)d_in[1];
  const float* Whh = (const float*)d_in[2];
  const float* bih = (const float*)d_in[3];
  const float* bhh = (const float*)d_in[4];
  float* out = (float*)d_out;

  unsigned long long* hbuf = (unsigned long long*)d_ws;                 // 262144 B
  unsigned int* flags = (unsigned int*)((char*)d_ws + 262144);          // 2048 u32

  hipLaunchKernelGGL(init_ws_kernel, dim3(64), dim3(256), 0, stream, hbuf, flags);
  hipLaunchKernelGGL(lstm_persistent, dim3(64), dim3(256), 0, stream,
                     x, Wih, Whh, bih, bhh, out, hbuf, flags);
}